// Round 8
// baseline (291.622 us; speedup 1.0000x reference)
//
#include <hip/hip_runtime.h>

// ---------------------------------------------------------------------------
// Batch-inner LeNet: lane = image, activations in [feature][N] layout.
// All weights are wave-uniform -> scalar loads (s_load, SGPR operands);
// zero LDS outside the transpose. XCD swizzle keeps an image-group's
// activations resident in one XCD's L2. Patch values are pinned in VGPRs
// via volatile asm so the register allocator cannot rematerialize the
// loads to chase a higher occupancy tier (R5-R7: VGPR 60/76 + remat).
// ---------------------------------------------------------------------------

__device__ __forceinline__ int xcd_swizzle(int orig, int nwg) {
    // m204 bijective: xcd = orig%8 gets a contiguous newid range.
    int xcd = orig & 7, q = nwg >> 3, r = nwg & 7;
    int base = (xcd < r) ? xcd * (q + 1) : r * (q + 1) + (xcd - r) * q;
    return base + (orig >> 3);
}

// Transpose x[nc,784] -> xt[1024,nc] (zero-padded 32x32 image layout).
// grid = (16, nc/64).
__global__ __launch_bounds__(256) void transpose_x(
    const float* __restrict__ x, float* __restrict__ xt, int nc)
{
    __shared__ float t[64][65];
    const int tx = threadIdx.x & 63, ty = threadIdx.x >> 6;  // ty 0..3
    const int p0 = blockIdx.x * 64, n0 = blockIdx.y * 64;
    #pragma unroll
    for (int rr = 0; rr < 16; ++rr) {
        int nl = rr * 4 + ty;
        int pp = p0 + tx;              // padded pixel 0..1023
        int pr = pp >> 5, pc = pp & 31;
        float v = 0.f;
        if (pr >= 2 && pr < 30 && pc >= 2 && pc < 30)
            v = x[(size_t)(n0 + nl) * 784 + (pr - 2) * 28 + (pc - 2)];
        t[tx][nl] = v;
    }
    __syncthreads();
    #pragma unroll
    for (int rr = 0; rr < 16; ++rr) {
        int pl = rr * 4 + ty;
        xt[(size_t)(p0 + pl) * nc + n0 + tx] = t[pl][tx];
    }
}

// conv1(pad2)+relu+pool. Flat grid = 196*(nc/512); 2 consecutive images per
// thread via float2, patch pinned in VGPRs. Weights via scalar pipe.
__global__ __launch_bounds__(256, 4) void conv1_bt(
    const float* __restrict__ xt, const float* __restrict__ c1w,
    const float* __restrict__ c1b, float* __restrict__ p1t, int nc)
{
    const int newid = xcd_swizzle(blockIdx.x, gridDim.x);
    const int grp = newid / 196, pos = newid - grp * 196;
    const int py = pos / 14, px = pos - py * 14;
    const int img = grp * 512 + threadIdx.x * 2;
    const int pbase = (2 * py) * 32 + 2 * px; // top-left of 6x6 in padded img

    float2 p[36];
    #pragma unroll
    for (int r = 0; r < 6; ++r)
        #pragma unroll
        for (int cc = 0; cc < 6; ++cc)
            p[r * 6 + cc] =
                *(const float2*)&xt[(size_t)(pbase + r * 32 + cc) * nc + img];
    #pragma unroll
    for (int i = 0; i < 36; ++i)
        asm volatile("" : "+v"(p[i].x), "+v"(p[i].y));

    #pragma unroll
    for (int ch = 0; ch < 6; ++ch) {
        float w[25];
        const float* wp = c1w + ch * 25;     // uniform -> s_load
        #pragma unroll
        for (int k = 0; k < 25; ++k) w[k] = wp[k];
        float b = c1b[ch];
        float ma = -1e30f, mb = -1e30f;
        #pragma unroll
        for (int dy = 0; dy < 2; ++dy)
        #pragma unroll
        for (int dx = 0; dx < 2; ++dx) {
            float aa = b, ab = b;
            #pragma unroll
            for (int ky = 0; ky < 5; ++ky)
            #pragma unroll
            for (int kx = 0; kx < 5; ++kx) {
                float ww = w[ky * 5 + kx];
                float2 pv = p[(dy + ky) * 6 + dx + kx];
                aa += pv.x * ww;
                ab += pv.y * ww;
            }
            ma = fmaxf(ma, aa); mb = fmaxf(mb, ab);
        }
        float2 o2 = make_float2(fmaxf(ma, 0.f), fmaxf(mb, 0.f));
        *(float2*)&p1t[(size_t)(ch * 196 + pos) * nc + img] = o2;
    }
}

// conv2(valid)+relu+pool: 1 image/thread, 8 oc per BLOCK (pass = blockIdx
// component) -> live set acc(32)+pa(36)+temps ~ 90 VGPR, inside the 65-128
// occupancy tier; patch pinned via volatile asm so it cannot be remat'd.
// Flat grid = 50*(nc/256), XCD-swizzled. Feature order ch*25 + qy*5 + qx.
__global__ __launch_bounds__(256, 4) void conv2_bt(
    const float* __restrict__ p1t, const float* __restrict__ c2w,
    const float* __restrict__ c2b, float* __restrict__ ht, int nc)
{
    const int newid = xcd_swizzle(blockIdx.x, gridDim.x);
    const int grp = newid / 50, rem = newid - grp * 50;
    const int pass = rem / 25, pos = rem - pass * 25;
    const int qy = pos / 5, qx = pos - qy * 5;
    const int img = grp * 256 + threadIdx.x;
    const int y0 = 2 * qy, x0 = 2 * qx;

    float acc[32];
    #pragma unroll
    for (int i = 0; i < 32; ++i) acc[i] = 0.f;

    #pragma unroll 1
    for (int ci = 0; ci < 6; ++ci) {
        float pa[36];
        #pragma unroll
        for (int r = 0; r < 6; ++r)
            #pragma unroll
            for (int cc = 0; cc < 6; ++cc)
                pa[r * 6 + cc] =
                    p1t[(size_t)(ci * 196 + (y0 + r) * 14 + x0 + cc) * nc + img];
        #pragma unroll
        for (int i = 0; i < 36; ++i)
            asm volatile("" : "+v"(pa[i]));
        #pragma unroll
        for (int o8 = 0; o8 < 8; ++o8) {
            float w[25];
            const float* wp = c2w + ((pass * 8 + o8) * 6 + ci) * 25;
            #pragma unroll
            for (int k = 0; k < 25; ++k) w[k] = wp[k];
            #pragma unroll
            for (int ky = 0; ky < 5; ++ky)
            #pragma unroll
            for (int kx = 0; kx < 5; ++kx) {
                float ww = w[ky * 5 + kx];
                acc[o8*4+0] += pa[ky*6+kx]       * ww;
                acc[o8*4+1] += pa[ky*6+kx+1]     * ww;
                acc[o8*4+2] += pa[(ky+1)*6+kx]   * ww;
                acc[o8*4+3] += pa[(ky+1)*6+kx+1] * ww;
            }
        }
    }
    #pragma unroll
    for (int o8 = 0; o8 < 8; ++o8) {
        int oc = pass * 8 + o8;
        float b = c2b[oc];
        float m = fmaxf(fmaxf(acc[o8*4+0], acc[o8*4+1]),
                        fmaxf(acc[o8*4+2], acc[o8*4+3])) + b;
        ht[(size_t)(oc * 25 + pos) * nc + img] = fmaxf(m, 0.f);
    }
}

// fc1: a1t[o][n] = relu(sum_k ht[k][n]*f1w[o][k] + b). 2 img/thread (float2),
// 8 outs/block-group. Flat grid = 15*(nc/512), XCD-swizzled.
__global__ __launch_bounds__(256) void fc1_bt(
    const float* __restrict__ ht, const float* __restrict__ f1w,
    const float* __restrict__ f1b, float* __restrict__ a1t, int nc)
{
    const int newid = xcd_swizzle(blockIdx.x, gridDim.x);
    const int grp = newid / 15, og = newid - grp * 15;
    const int img = grp * 512 + threadIdx.x * 2;
    const float* wb = f1w + og * 8 * 400;

    float2 acc[8];
    #pragma unroll
    for (int j = 0; j < 8; ++j) acc[j] = make_float2(0.f, 0.f);

    #pragma unroll 4
    for (int k = 0; k < 400; ++k) {
        float2 hv = *(const float2*)&ht[(size_t)k * nc + img];
        #pragma unroll
        for (int j = 0; j < 8; ++j) {
            float w = wb[j * 400 + k];        // uniform -> s_load
            acc[j].x += hv.x * w;
            acc[j].y += hv.y * w;
        }
    }
    #pragma unroll
    for (int j = 0; j < 8; ++j) {
        int o = og * 8 + j;
        float b = f1b[o];
        float2 o2 = make_float2(fmaxf(acc[j].x + b, 0.f),
                                fmaxf(acc[j].y + b, 0.f));
        *(float2*)&a1t[(size_t)o * nc + img] = o2;
    }
}

// fc2: a2t[o][n] = relu(sum_k a1t[k][n]*f2w[o][k] + b). 7 outs x 12 groups.
__global__ __launch_bounds__(256) void fc2_bt(
    const float* __restrict__ a1t, const float* __restrict__ f2w,
    const float* __restrict__ f2b, float* __restrict__ a2t, int nc)
{
    const int newid = xcd_swizzle(blockIdx.x, gridDim.x);
    const int grp = newid / 12, og = newid - grp * 12;
    const int img = grp * 512 + threadIdx.x * 2;
    const float* wb = f2w + og * 7 * 120;

    float2 acc[7];
    #pragma unroll
    for (int j = 0; j < 7; ++j) acc[j] = make_float2(0.f, 0.f);

    #pragma unroll 4
    for (int k = 0; k < 120; ++k) {
        float2 hv = *(const float2*)&a1t[(size_t)k * nc + img];
        #pragma unroll
        for (int j = 0; j < 7; ++j) {
            float w = wb[j * 120 + k];
            acc[j].x += hv.x * w;
            acc[j].y += hv.y * w;
        }
    }
    #pragma unroll
    for (int j = 0; j < 7; ++j) {
        int o = og * 7 + j;
        float b = f2b[o];
        float2 o2 = make_float2(fmaxf(acc[j].x + b, 0.f),
                                fmaxf(acc[j].y + b, 0.f));
        *(float2*)&a2t[(size_t)o * nc + img] = o2;
    }
}

// fc3 (no relu): embt[o][n0+n] = sum_k a2t[k][n]*f3w[o][k] + b.
// embt is the FULL-N buffer [64][Ntot]; chunk writes at offset n0.
__global__ __launch_bounds__(256) void fc3_bt(
    const float* __restrict__ a2t, const float* __restrict__ f3w,
    const float* __restrict__ f3b, float* __restrict__ embt,
    int nc, int Ntot, int n0)
{
    const int newid = xcd_swizzle(blockIdx.x, gridDim.x);
    const int grp = newid / 8, og = newid - grp * 8;
    const int limg = grp * 512 + threadIdx.x * 2;
    const float* wb = f3w + og * 8 * 84;

    float2 acc[8];
    #pragma unroll
    for (int j = 0; j < 8; ++j) acc[j] = make_float2(0.f, 0.f);

    #pragma unroll 4
    for (int k = 0; k < 84; ++k) {
        float2 hv = *(const float2*)&a2t[(size_t)k * nc + limg];
        #pragma unroll
        for (int j = 0; j < 8; ++j) {
            float w = wb[j * 84 + k];
            acc[j].x += hv.x * w;
            acc[j].y += hv.y * w;
        }
    }
    #pragma unroll
    for (int j = 0; j < 8; ++j) {
        int o = og * 8 + j;
        float b = f3b[o];
        float2 o2 = make_float2(acc[j].x + b, acc[j].y + b);
        *(float2*)&embt[(size_t)o * Ntot + n0 + limg] = o2;
    }
}

// Head: thread = image. Serial 64-wide softmax in registers; proto via
// uniform s_load of embt[o][0]. Stores 64 consecutive floats per thread.
__global__ __launch_bounds__(256) void proto_head_t(
    const float* __restrict__ embt, float* __restrict__ out, int N)
{
    const int img = blockIdx.x * 256 + threadIdx.x;
    float v[64];
    float m = -1e30f;
    #pragma unroll
    for (int o = 0; o < 64; ++o) {
        v[o] = embt[(size_t)o * N + img];
        m = fmaxf(m, v[o]);
    }
    float s = 0.f;
    #pragma unroll
    for (int o = 0; o < 64; ++o) {
        v[o] = __expf(v[o] - m);
        s += v[o];
    }
    float inv = __frcp_rn(s);
    #pragma unroll
    for (int o = 0; o < 64; o += 4) {
        float4 r;
        r.x = fabsf(v[o+0] * inv - embt[(size_t)(o+0) * N] * 0.2f);
        r.y = fabsf(v[o+1] * inv - embt[(size_t)(o+1) * N] * 0.2f);
        r.z = fabsf(v[o+2] * inv - embt[(size_t)(o+2) * N] * 0.2f);
        r.w = fabsf(v[o+3] * inv - embt[(size_t)(o+3) * N] * 0.2f);
        *(float4*)&out[(size_t)img * 64 + o] = r;
    }
}

extern "C" void kernel_launch(void* const* d_in, const int* in_sizes, int n_in,
                              void* d_out, int out_size, void* d_ws, size_t ws_size,
                              hipStream_t stream)
{
    const float* x   = (const float*)d_in[0];
    const float* c1w = (const float*)d_in[1];
    const float* c1b = (const float*)d_in[2];
    const float* c2w = (const float*)d_in[3];
    const float* c2b = (const float*)d_in[4];
    const float* f1w = (const float*)d_in[5];
    const float* f1b = (const float*)d_in[6];
    const float* f2w = (const float*)d_in[7];
    const float* f2b = (const float*)d_in[8];
    const float* f3w = (const float*)d_in[9];
    const float* f3b = (const float*)d_in[10];
    float* out = (float*)d_out;

    const int N = in_sizes[0] / 784;          // 20480
    float* base = (float*)d_ws;

    // Region A: xt[1024][nc] -> reused as ht[400][nc]
    // Region B: p1t[1176][nc] -> reused as a1t[120][nc] + a2t[84][nc]
    // embt[64][N] persistent.  bytes = 8800nc + 256N
    int c = 40;
    const int cands[] = {1, 2, 4, 5, 8, 10, 20, 40};
    for (int k = 0; k < 8; ++k) {
        int cd = cands[k];
        if (N % cd) continue;
        int ncq = N / cd;
        if (ncq % 512) continue;
        size_t need = (size_t)8800 * ncq + (size_t)256 * N;
        if (need <= ws_size) { c = cd; break; }
    }
    const int nc = N / c;

    float* xt   = base;                        // [1024][nc] padded images
    float* p1t  = base + (size_t)1024 * nc;    // [1176][nc]
    float* ht_  = base;                        // [400][nc]  (over xt)
    float* a1t  = p1t;                         // [120][nc]  (over p1t)
    float* a2t  = p1t + (size_t)120 * nc;      // [84][nc]
    float* embt = base + (size_t)2200 * nc;    // [64][N]

    for (int k = 0; k < c; ++k) {
        int n0 = k * nc;
        transpose_x<<<dim3(16, nc / 64), 256, 0, stream>>>(
            x + (size_t)n0 * 784, xt, nc);
        conv1_bt<<<196 * (nc / 512), 256, 0, stream>>>(
            xt, c1w, c1b, p1t, nc);
        conv2_bt<<<50 * (nc / 256), 256, 0, stream>>>(
            p1t, c2w, c2b, ht_, nc);
        fc1_bt<<<15 * (nc / 512), 256, 0, stream>>>(
            ht_, f1w, f1b, a1t, nc);
        fc2_bt<<<12 * (nc / 512), 256, 0, stream>>>(
            a1t, f2w, f2b, a2t, nc);
        fc3_bt<<<8 * (nc / 512), 256, 0, stream>>>(
            a2t, f3w, f3b, embt, nc, N, n0);
    }
    proto_head_t<<<N / 256, 256, 0, stream>>>(embt, out, N);
}